// Round 3
// baseline (266.489 us; speedup 1.0000x reference)
//
#include <hip/hip_runtime.h>

#define EMBED_D 128
#define KNBR 50
#define NROWS 102     // 100 data rows (k*2+half) + 2 zero rows (100,101)
#define ZK 50         // sentinel k for tail lanes -> LDS rows 100/101
#define NTF 52        // Ns_T row stride in f32: [d][row], 52 rows (only 0..51 stored; 0..49 read)
#define XSTR 264      // (fallback only)
#define NSTR 136      // (fallback only)
#define MROWS 64

typedef __attribute__((ext_vector_type(8))) short short8;    // 8 bf16 (MFMA A/B frag)
typedef __attribute__((ext_vector_type(4))) float floatx4;   // MFMA C/D frag

__device__ __forceinline__ float b2f(unsigned short u) {
    union { unsigned int i; float f; } v;
    v.i = ((unsigned int)u) << 16;
    return v.f;
}
__device__ __forceinline__ unsigned short f2b(float f) {
    union { float f; unsigned int i; } v;
    v.f = f;
    return (unsigned short)((v.i + 0x7fffu + ((v.i >> 16) & 1u)) >> 16);  // RNE, finite-only
}

// 16-lane DPP all-reduce sum on the VALU pipe (not ds_swizzle/LDS).
__device__ __forceinline__ float dpp_row_sum16(float v) {
    int y;
    y = __builtin_amdgcn_update_dpp(0, __builtin_bit_cast(int, v), 0xB1, 0xF, 0xF, true);
    v += __builtin_bit_cast(float, y);
    y = __builtin_amdgcn_update_dpp(0, __builtin_bit_cast(int, v), 0x4E, 0xF, 0xF, true);
    v += __builtin_bit_cast(float, y);
    y = __builtin_amdgcn_update_dpp(0, __builtin_bit_cast(int, v), 0x124, 0xF, 0xF, true);
    v += __builtin_bit_cast(float, y);
    y = __builtin_amdgcn_update_dpp(0, __builtin_bit_cast(int, v), 0x128, 0xF, 0xF, true);
    v += __builtin_bit_cast(float, y);
    return v;
}

// bf16 emb data (N(0,0.02)) decodes to |v| < 0.15 everywhere; fp32 data has
// random low-mantissa words -> some finite |v| >= 1.0 with P ~ 1-2e-10.
__device__ __forceinline__ bool detect_bf16(const unsigned short* p) {
    float mx = 0.f;
#pragma unroll
    for (int i = 0; i < 64; ++i) {
        const float a = fabsf(b2f(p[i]));
        if (a < 3.0e38f && a > mx) mx = a;
    }
    return mx < 1.0f;
}

// ---------------- preprocessing (r12, proven: Wg/tiny/weights first, emb last) ----------------

struct TinyTensors {
    const void* src[6];
    unsigned short* dst[6];
    int n[6];
};

__device__ __forceinline__ void conv_chunk(const void* src, unsigned short* dst,
                                           long i, bool isbf) {
    if (isbf) {
        *(short8*)(dst + i * 8) = *(const short8*)((const unsigned short*)src + i * 8);
    } else {
        const float* p = (const float*)src + i * 8;
        const floatx4 a = *(const floatx4*)p;
        const floatx4 c = *(const floatx4*)(p + 4);
        short8 r;
        r[0] = (short)f2b(a[0]); r[1] = (short)f2b(a[1]);
        r[2] = (short)f2b(a[2]); r[3] = (short)f2b(a[3]);
        r[4] = (short)f2b(c[0]); r[5] = (short)f2b(c[1]);
        r[6] = (short)f2b(c[2]); r[7] = (short)f2b(c[3]);
        *(short8*)(dst + i * 8) = r;
    }
}

__global__ void convert_all_kernel(const void* __restrict__ emb_src, unsigned short* __restrict__ emb_dst,
                                   long n8, int nEmb,
                                   const void* __restrict__ gw_src, unsigned short* __restrict__ gw_dst,
                                   long gw8,
                                   const void* __restrict__ w1_src, unsigned short* __restrict__ w1_dst,
                                   long w18,
                                   const void* __restrict__ gwb_src, const void* __restrict__ b1_src,
                                   unsigned short* __restrict__ wg_dst,   // [64][256] bf16
                                   float* __restrict__ bg_dst,            // [64] f32
                                   int* __restrict__ flag_dst,            // [1] precomputed dtype flag
                                   TinyTensors tt) {
    __shared__ int isbfS;
    if (threadIdx.x == 0) isbfS = detect_bf16((const unsigned short*)emb_src) ? 1 : 0;
    __syncthreads();
    const bool isbf = (isbfS != 0);
    const int bid = blockIdx.x;

    if (bid < 64) {
        // Wg[j][f] = sum_d W1[j][d]*gw[d][f]; bg[j] = W1[j].gwb + b1[j].
        const int j = bid;
        const int f = threadIdx.x;
        float a = 0.f;
        if (isbf) {
            const unsigned short* w1u = (const unsigned short*)w1_src;
            const unsigned short* gwu = (const unsigned short*)gw_src;
            for (int d = 0; d < EMBED_D; ++d)
                a += b2f(w1u[j * EMBED_D + d]) * b2f(gwu[(long)d * 256 + f]);
        } else {
            const float* w1f = (const float*)w1_src;
            const float* gwf = (const float*)gw_src;
            for (int d = 0; d < EMBED_D; ++d)
                a += w1f[j * EMBED_D + d] * gwf[(long)d * 256 + f];
        }
        wg_dst[j * 256 + f] = f2b(a);
        if (f == 0) {
            float s = 0.f;
            if (isbf) {
                const unsigned short* w1u = (const unsigned short*)w1_src;
                const unsigned short* gu = (const unsigned short*)gwb_src;
                for (int d = 0; d < EMBED_D; ++d) s += b2f(w1u[j * EMBED_D + d]) * b2f(gu[d]);
                bg_dst[j] = s + b2f(((const unsigned short*)b1_src)[j]);
            } else {
                const float* w1f = (const float*)w1_src;
                const float* gf = (const float*)gwb_src;
                for (int d = 0; d < EMBED_D; ++d) s += w1f[j * EMBED_D + d] * gf[d];
                bg_dst[j] = s + ((const float*)b1_src)[j];
            }
        }
    } else if (bid == 64) {
        if (threadIdx.x == 0) *flag_dst = isbf ? 1 : 0;
#pragma unroll
        for (int ti = 0; ti < 6; ++ti) {
            const int n = tt.n[ti];
            for (int i = threadIdx.x; i < n; i += 256) {
                const float v = isbf ? b2f(((const unsigned short*)tt.src[ti])[i])
                                     : ((const float*)tt.src[ti])[i];
                tt.dst[ti][i] = f2b(v);
            }
        }
    } else if (bid < 85) {
        const long q = (long)(bid - 65) * 256 + threadIdx.x;   // gw8+w18 = 5120 chunks
        if (q < gw8) conv_chunk(gw_src, gw_dst, q, isbf);
        else if (q < gw8 + w18) conv_chunk(w1_src, w1_dst, q - gw8, isbf);
    } else {
        const long i0 = (long)(bid - 85) * 512 + threadIdx.x;  // 2 chunks/thread
        if (i0 < n8) conv_chunk(emb_src, emb_dst, i0, isbf);
        const long i1 = i0 + 256;
        if (i1 < n8) conv_chunk(emb_src, emb_dst, i1, isbf);
    }
}

// ---------------- main kernel ----------------
// r14 post-mortem: occupancy 50% (5 waves/SIMD) is the register-structural cap
// (48 VGPR + 48 AGPR = 96 = 512/5 bucket; the 3-chain accumulator is minimal).
// The total-vs-main gap is ~100 us FIXED (harness reset dispatches + ~13 us
// convert) -- all leverage is in this kernel.
// r15 change: P0 gather via global_load_lds width=16 (no VGPR round-trip, no
// ds_writes) -> all 7 row-group loads issue back-to-back instead of ~3-4 deep
// under the 48-VGPR cap. Requires UNPADDED X rows (wave writes base+lane*16:
// 64 lanes = 4 complete 256B rows/instruction; 25 wave-insts cover 100 rows).
// Bank fix per rule #21 (both-sides-or-neither): global SOURCE chunk j^(r&15)
// lands in linear LDS slot j; P1 reads slot jc^(r&15). A-read lanes then hit
// 4 bank-groups x 4 lanes = 4-way, same class as the old padded layout
// (measured ~0 conflict cost). Plus: initial B0/B1 frags hoisted above the
// barrier (no LDS dependence), s_setprio(1) around the MFMA triple (5
// independent-phase blocks/CU = the regime where T5 measured +4-7%).

__global__ __launch_bounds__(256, 5)
void embed_matcher_fast(const int* __restrict__ entity, const int* __restrict__ conn,
                        const unsigned short* __restrict__ emb,   // bf16 staged
                        const unsigned short* __restrict__ gw,    // [128][256] bf16
                        const unsigned short* __restrict__ wg,    // [64][256] bf16 (W1.gw)
                        const float* __restrict__ bgp,            // [64] f32 (W1.gwb + b1)
                        const unsigned short* __restrict__ gwb,
                        const unsigned short* __restrict__ gcnb,
                        const unsigned short* __restrict__ w2,
                        const unsigned short* __restrict__ b2v,
                        const unsigned short* __restrict__ temp,
                        const int* __restrict__ flagp,            // precomputed output-dtype flag
                        void* __restrict__ out)
{
    // Phase 1: X tile 102 x 128 u16 (UNPADDED) = 26112 B, swizzled chunks.
    // Phase 2: Ns_T 128 x 52 f32 = 26624 B (sizes the union buffer).
    __shared__ __align__(16) float NsF[128 * NTF];   // 26624 B union buffer
    __shared__ __align__(16) float selfE[EMBED_D];
    __shared__ float scoresP[4 * MROWS];   // per-wave partials (no LDS atomics)
    __shared__ float glP[4 * MROWS];
    __shared__ __align__(16) float attnS[MROWS];
    __shared__ int flagS;

    unsigned short* Xs = (unsigned short*)NsF;   // phase-1 alias (26112 <= 26624 B)

    const int t = threadIdx.x;
    const int b = blockIdx.x;
    const int lane = t & 63;
    const int wave = t >> 6;
    const int l15 = lane & 15;
    const int quad = lane >> 4;
    const int cbase = b * (KNBR * 2);

    const int k3 = 48 + l15;
    const int rowk3 = (k3 < KNBR) ? k3 : ZK;             // m=3 tail -> zero rows

    floatx4 acc[4][3];                                   // [m][T]: T=0,1 gw-slices, T=2 wg
    const floatx4 fzero = {0.f, 0.f, 0.f, 0.f};
#pragma unroll
    for (int m = 0; m < 4; ++m)
#pragma unroll
        for (int T = 0; T < 3; ++T) acc[m][T] = fzero;

    // ---- P0: gather via global_load_lds (row-group g = 4*i+wave owns 4 rows) ----
    // LDS slot (r, p) receives global chunk p^(r&15) of row sym[r]: lane L of
    // group g covers row r = g*4 + (L>>4), slot p = L&15, dst byte g*1024+L*16.
    {
        int syms[7];
#pragma unroll
        for (int i = 0; i < 7; ++i) {
            const int g = 4 * i + wave;
            const int r = g * 4 + (lane >> 4);
            syms[i] = (g < 25) ? conn[cbase + r] : 0;
        }
#pragma unroll
        for (int i = 0; i < 7; ++i) {
            const int g = 4 * i + wave;              // wave-uniform predicate
            if (g < 25) {
                const int r = g * 4 + (lane >> 4);
                const int j = l15 ^ (r & 15);        // inverse-swizzled source chunk
                const unsigned short* gp = emb + (long)syms[i] * EMBED_D + j * 8;
                __builtin_amdgcn_global_load_lds(
                    (const __attribute__((address_space(1))) void*)gp,
                    (__attribute__((address_space(3))) void*)(Xs + g * 4 * 128),
                    16, 0, 0);
            }
        }
        const short8 z8 = {0, 0, 0, 0, 0, 0, 0, 0};
        if (t < 32)                                  // zero rows 100,101: 512 B
            *(short8*)(Xs + 100 * 128 + t * 8) = z8;
        if (t < EMBED_D) selfE[t] = b2f(emb[(long)entity[b] * EMBED_D + t]);
        if (t == 0) flagS = *flagp;
    }

    const unsigned short* gB0 = gw + (wave * 32 + l15) * 256;       // B row, n-tile 0
    const unsigned short* gB1 = gB0 + 16 * 256;                     // n-tile 1
    const unsigned short* gWg = wg + (wave * 16 + l15) * 256;       // wg n-tile

    // Initial B frags: no LDS dependence -> issue before the barrier so their
    // latency hides under the gather drain.
    short8 B0c = *(const short8*)(gB0 + quad * 8);
    short8 B1c = *(const short8*)(gB1 + quad * 8);

    __syncthreads();   // drains global_load_lds (compiler emits vmcnt(0))

    // ---- P1: C[64 x 160] = X(64x256) . [gw | Wg]^T ----
    // B0/B1 pipelined 1 deep; Bg loaded in-loop (L1/L2-hot 32KB table).
    // A-reads use the swizzled slot jc^(r&15).
#pragma unroll
    for (int ft = 0; ft < 8; ++ft) {
        const short8 Bgc = *(const short8*)(gWg + ft * 32 + quad * 8);
        short8 B0n, B1n;
        if (ft < 7) {                                    // prefetch next B frags
            const int kn = (ft + 1) * 32 + quad * 8;
            B0n = *(const short8*)(gB0 + kn);
            B1n = *(const short8*)(gB1 + kn);
        }
        const int half = ft >> 2;
        const int jc = (ft & 3) * 4 + quad;              // 16B chunk index in row
        short8 A[4];
#pragma unroll
        for (int m = 0; m < 3; ++m) {
            const int r = (m * 16 + l15) * 2 + half;
            A[m] = *(const short8*)(Xs + r * 128 + ((jc ^ (r & 15)) << 3));
        }
        {
            const int r = rowk3 * 2 + half;
            A[3] = *(const short8*)(Xs + r * 128 + ((jc ^ (r & 15)) << 3));
        }
        __builtin_amdgcn_s_setprio(1);
#pragma unroll
        for (int m = 0; m < 4; ++m) {
            acc[m][0] = __builtin_amdgcn_mfma_f32_16x16x32_bf16(A[m], B0c, acc[m][0], 0, 0, 0);
            acc[m][1] = __builtin_amdgcn_mfma_f32_16x16x32_bf16(A[m], B1c, acc[m][1], 0, 0, 0);
            acc[m][2] = __builtin_amdgcn_mfma_f32_16x16x32_bf16(A[m], Bgc, acc[m][2], 0, 0, 0);
        }
        __builtin_amdgcn_s_setprio(0);
        if (ft < 7) { B0c = B0n; B1c = B1n; }
    }
    __syncthreads();   // X dead; buffer becomes Ns_T (f32)

    // ---- Epilogue: bias + fp32 Ns_T b128 stores + score & gate partials via DPP ----
    // C/D layout: lane (l15,quad) holds rows m*16+quad*4+r, cols wave*32+T*16+l15
    // (T=2 -> wg col wave*16+l15).
    // Rows >= 52 are never read (softmax masks k >= 50), so m==3 stores only
    // quad==0 (rows 48..51) to stay inside the NTF=52 stride.
    {
        const int dcol0 = wave * 32 + l15;
        const int dcol1 = dcol0 + 16;
        const float bias0 = b2f(gwb[dcol0]);
        const float bias1 = b2f(gwb[dcol1]);
        const float se0 = selfE[dcol0];
        const float se1 = selfE[dcol1];
        const float bgj = bgp[wave * 16 + l15];
        const float w2j = b2f(w2[wave * 16 + l15]);
#pragma unroll
        for (int m = 0; m < 4; ++m) {
            const int rbase = m * 16 + quad * 4;
            floatx4 v0, v1;
            float sc[4], gl[4];
#pragma unroll
            for (int r = 0; r < 4; ++r) {
                v0[r] = acc[m][0][r] + bias0;
                v1[r] = acc[m][1][r] + bias1;
                sc[r] = se0 * v0[r] + se1 * v1[r];
                gl[r] = fmaxf(acc[m][2][r] + bgj, 0.f) * w2j;
            }
            if (m < 3 || quad == 0) {
                *(floatx4*)(NsF + dcol0 * NTF + rbase) = v0;
                *(floatx4*)(NsF + dcol1 * NTF + rbase) = v1;
            }
#pragma unroll
            for (int r = 0; r < 4; ++r) {
                sc[r] = dpp_row_sum16(sc[r]);   // VALU-pipe 16-lane reduce
                gl[r] = dpp_row_sum16(gl[r]);
            }
            const float sv = (l15 == 0) ? sc[0] : ((l15 == 1) ? sc[1] : ((l15 == 2) ? sc[2] : sc[3]));
            const float gv = (l15 == 0) ? gl[0] : ((l15 == 1) ? gl[1] : ((l15 == 2) ? gl[2] : gl[3]));
            if (l15 < 4) {
                scoresP[wave * MROWS + rbase + l15] = sv;
                glP[wave * MROWS + rbase + l15] = gv;
            }
        }
    }
    __syncthreads();

    // ---- softmax + gate fold (wave 0) ----
    if (t < 64) {
        const float ssum = scoresP[t] + scoresP[64 + t] + scoresP[128 + t] + scoresP[192 + t];
        const float s = (t < KNBR) ? ssum * 0.088388347648318447f : -INFINITY;  // /sqrt(128)
        float mx = s;
#pragma unroll
        for (int o = 32; o > 0; o >>= 1) mx = fmaxf(mx, __shfl_xor(mx, o));
        const float e = (t < KNBR) ? expf(s - mx) : 0.f;
        float sum = e;
#pragma unroll
        for (int o = 32; o > 0; o >>= 1) sum += __shfl_xor(sum, o);
        float a = e / sum;
        if (t < KNBR) {
            const float invT = 1.0f / b2f(temp[0]);
            const float logit = glP[t] + glP[64 + t] + glP[128 + t] + glP[192 + t] + b2f(b2v[0]);
            a *= 1.0f / (1.0f + expf(-logit * invT));
        }
        attnS[t] = a;   // 0 for t >= KNBR
    }
    __syncthreads();

    // ---- P4b: out[d] = tanh(max_k(attn*nbr) + gcn_b), b128 fp32 reads ----
    if (t < EMBED_D) {
        const float* nr = NsF + t * NTF;
        float mx = -INFINITY;
#pragma unroll
        for (int c = 0; c < 12; ++c) {                   // rows 0..47
            const floatx4 nv = *(const floatx4*)(nr + c * 4);
            const floatx4 av = *(const floatx4*)(attnS + c * 4);
#pragma unroll
            for (int j = 0; j < 4; ++j)
                mx = fmaxf(mx, av[j] * nv[j]);
        }
        mx = fmaxf(mx, attnS[48] * nr[48]);
        mx = fmaxf(mx, attnS[49] * nr[49]);
        const float o = tanhf(mx + b2f(gcnb[t]));
        if (flagS)
            ((unsigned short*)out)[(long)b * EMBED_D + t] = f2b(o);
        else
            ((float*)out)[(long)b * EMBED_D + t] = o;
    }
}

// ---------------- fallback (round-2 proven kernel, used only if ws too small) ----------------

template <bool BF16IN>
__device__ __forceinline__ short8 load8g(const void* base, long off) {
    if constexpr (BF16IN) {
        return *(const short8*)((const unsigned short*)base + off);
    } else {
        const float* p = (const float*)base + off;
        const floatx4 a = *(const floatx4*)p;
        const floatx4 c = *(const floatx4*)(p + 4);
        short8 r;
        r[0] = (short)f2b(a[0]); r[1] = (short)f2b(a[1]);
        r[2] = (short)f2b(a[2]); r[3] = (short)f2b(a[3]);
        r[4] = (short)f2b(c[0]); r[5] = (short)f2b(c[1]);
        r[6] = (short)f2b(c[2]); r[7] = (short)f2b(c[3]);
        return r;
    }
}
template <bool BF16IN>
__device__ __forceinline__ float loadSg(const void* base, long off) {
    if constexpr (BF16IN) return b2f(((const unsigned short*)base)[off]);
    else return ((const float*)base)[off];
}

template <bool BF16IN>
__device__ __forceinline__ void body_fb(
    const int* entity, const int* conn, const void* emb, const void* gw,
    const void* gwb, const void* gcnb, const void* w1, const void* b1,
    const void* w2, const void* b2, const void* temp, void* out,
    unsigned short* Xs, unsigned short* Ns,
    float* selfE, float* scoresS, float* attnS, float* gsumS)
{
    const int t = threadIdx.x, b = blockIdx.x;
    const int lane = t & 63, wave = t >> 6, l15 = lane & 15, quad = lane >> 4;
    short8 Bfrag[8][2];
#pragma unroll
    for (int ft = 0; ft < 8; ++ft)
#pragma unroll
        for (int nn = 0; nn < 2; ++nn)
            Bfrag[ft][nn] = load8g<BF16IN>(gw, (wave * 32 + nn * 16 + l15) * 256 + ft * 32 + quad * 8);
    short8 W1frag[4];
#pragma unroll
    for (int ft = 0; ft < 4; ++ft)
        W1frag[ft] = load8g<BF16IN>(w1, (wave * 16 + l15) * 128 + ft * 32 + quad * 8);
    const float b1j = loadSg<BF16IN>(b1, wave * 16 + l15);
    const float w2j = loadSg<BF16IN>(w2, wave * 16 + l15);
    {
        const int cbase = b * (KNBR * 2);
        for (int c = t; c < KNBR * 2 * 16; c += 256) {
            const int r = c >> 4, j = c & 15;
            const int sym = conn[cbase + r];
            *(short8*)(Xs + (r >> 1) * XSTR + (r & 1) * 128 + j * 8) =
                load8g<BF16IN>(emb, (long)sym * EMBED_D + j * 8);
        }
        for (int i = t; i < (MROWS - KNBR) * 256; i += 256)
            Xs[(KNBR + (i >> 8)) * XSTR + (i & 255)] = 0;
        if (t < EMBED_D) selfE[t] = loadSg<BF16IN>(emb, (long)entity[b] * EMBED_D + t);
        if (t < MROWS) gsumS[t] = loadSg<BF16IN>(b2, 0);
    }
    __syncthreads();
    floatx4 acc[4][2];
    const floatx4 fzero = {0.f, 0.f, 0.f, 0.f};
#pragma unroll
    for (int m = 0; m < 4; ++m)
#pragma unroll
        for (int nn = 0; nn < 2; ++nn) acc[m][nn] = fzero;
#pragma unroll
    for (int ft = 0; ft < 8; ++ft) {
        short8 A[4];
#pragma unroll
        for (int m = 0; m < 4; ++m)
            A[m] = *(const short8*)(Xs + (m * 16 + l15) * XSTR + ft * 32 + quad * 8);
#pragma unroll
        for (int m = 0; m < 4; ++m)
#pragma unroll
            for (int nn = 0; nn < 2; ++nn)
                acc[m][nn] = __builtin_amdgcn_mfma_f32_16x16x32_bf16(A[m], Bfrag[ft][nn], acc[m][nn], 0, 0, 0);
    }
#pragma unroll
    for (int nn = 0; nn < 2; ++nn) {
        const int dcol = wave * 32 + nn * 16 + l15;
        const float bias = loadSg<BF16IN>(gwb, dcol);
#pragma unroll
        for (int m = 0; m < 4; ++m)
#pragma unroll
            for (int r = 0; r < 4; ++r)
                Ns[(m * 16 + quad * 4 + r) * NSTR + dcol] = f2b(acc[m][nn][r] + bias);
    }
    __syncthreads();
    {
        const int k = t >> 2, q = t & 3;
        float p = 0.f;
        if (k < KNBR) {
            const unsigned short* nr = Ns + k * NSTR + q * 32;
            const float* se = selfE + q * 32;
#pragma unroll
            for (int i = 0; i < 32; ++i) p += se[i] * b2f(nr[i]);
        }
        p += __shfl_xor(p, 1);
        p += __shfl_xor(p, 2);
        if (k < KNBR && q == 0) scoresS[k] = p * 0.088388347648318447f;
    }
    __syncthreads();
    if (t < 64) {
        const float s = (t < KNBR) ? scoresS[t] : -INFINITY;
        float mx = s;
#pragma unroll
        for (int o = 32; o > 0; o >>= 1) mx = fmaxf(mx, __shfl_xor(mx, o));
        const float e = (t < KNBR) ? expf(s - mx) : 0.f;
        float sum = e;
#pragma unroll
        for (int o = 32; o > 0; o >>= 1) sum += __shfl_xor(sum, o);
        attnS[t] = e / sum;
    }
    floatx4 acc2[4];
#pragma unroll
    for (int m = 0; m < 4; ++m) acc2[m] = fzero;
#pragma unroll
    for (int ft = 0; ft < 4; ++ft) {
        short8 A2[4];
#pragma unroll
        for (int m = 0; m < 4; ++m)
            A2[m] = *(const short8*)(Ns + (m * 16 + l15) * NSTR + ft * 32 + quad * 8);
#pragma unroll
        for (int m = 0; m < 4; ++m)
            acc2[m] = __builtin_amdgcn_mfma_f32_16x16x32_bf16(A2[m], W1frag[ft], acc2[m], 0, 0, 0);
    }
#pragma unroll
    for (int m = 0; m < 4; ++m)
#pragma unroll
        for (int r = 0; r < 4; ++r) {
            float c = fmaxf(acc2[m][r] + b1j, 0.f) * w2j;
            c += __shfl_xor(c, 1); c += __shfl_xor(c, 2);
            c += __shfl_xor(c, 4); c += __shfl_xor(c, 8);
            if (l15 == 0) atomicAdd(&gsumS[m * 16 + quad * 4 + r], c);
        }
    __syncthreads();
    if (t < KNBR) {
        const float invT = 1.0f / loadSg<BF16IN>(temp, 0);
        attnS[t] *= 1.0f / (1.0f + expf(-gsumS[t] * invT));
    }
    __syncthreads();
    if (t < EMBED_D) {
        float mx = -INFINITY;
        for (int k = 0; k < KNBR; ++k)
            mx = fmaxf(mx, attnS[k] * b2f(Ns[k * NSTR + t]));
        const float o = tanhf(mx + loadSg<BF16IN>(gcnb, t));
        if constexpr (BF16IN)
            ((unsigned short*)out)[(long)b * EMBED_D + t] = f2b(o);
        else
            ((float*)out)[(long)b * EMBED_D + t] = o;
    }
}

__global__ __launch_bounds__(256, 2)
void embed_matcher_fallback(const int* entity, const int* conn, const void* emb,
                            const void* gw, const void* gwb, const void* gcnb,
                            const void* w1, const void* b1, const void* w2,
                            const void* b2, const void* temp, void* out)
{
    __shared__ __align__(16) unsigned short Xs[MROWS * XSTR];
    __shared__ __align__(16) unsigned short Ns[MROWS * NSTR];
    __shared__ float selfE[EMBED_D];
    __shared__ float scoresS[MROWS];
    __shared__ float attnS[MROWS];
    __shared__ float gsumS[MROWS];
    if (detect_bf16((const unsigned short*)emb))
        body_fb<true>(entity, conn, emb, gw, gwb, gcnb, w1, b1, w2, b2, temp, out,
                      Xs, Ns, selfE, scoresS, attnS, gsumS);
    else
        body_fb<false>(entity, conn, emb, gw, gwb, gcnb, w1, b1, w2, b2, temp, out,
                       Xs, Ns, selfE, scoresS, attnS, gsumS);
}

// ---------------- launcher ----------------

static inline size_t align256(size_t x) { return (x + 255) & ~(size_t)255; }

extern "C" void kernel_launch(void* const* d_in, const int* in_sizes, int n_in,
                              void* d_out, int out_size, void* d_ws, size_t ws_size,
                              hipStream_t stream) {
    (void)n_in; (void)out_size;
    const int B = in_sizes[0];  // 8192

    // ws layout: bf16 copies of all float tensors + Wg (bf16) + bg (f32) + flag
    const long n_emb = in_sizes[2];
    size_t off[9], cur = 0;
    const int ns[8] = {in_sizes[3], in_sizes[4], in_sizes[5], in_sizes[6],
                       in_sizes[7], in_sizes[8], in_sizes[9], in_sizes[10]};
    off[0] = 0; cur = align256((size_t)n_emb * 2);                      // emb
    for (int i = 0; i < 8; ++i) { off[i + 1] = cur; cur = align256(cur + (size_t)ns[i] * 2); }
    const size_t off_wg = cur; cur = align256(cur + 64 * 256 * 2);      // Wg bf16
    const size_t off_bg = cur; cur = align256(cur + 64 * 4);            // bg f32
    const size_t off_fl = cur; cur = align256(cur + 4);                 // dtype flag

    if (ws_size < cur) {
        embed_matcher_fallback<<<B, 256, 0, stream>>>(
            (const int*)d_in[0], (const int*)d_in[1],
            d_in[2], d_in[3], d_in[4], d_in[5],
            d_in[6], d_in[7], d_in[8], d_in[9], d_in[10], d_out);
        return;
    }

    char* ws = (char*)d_ws;
    unsigned short* emb_b = (unsigned short*)(ws + off[0]);

    // tiny tensors: gwb, gcnb, b1, w2, b2, temp  (input idx 4,5,7,8,9,10)
    TinyTensors tt;
    const int tin[6] = {4, 5, 7, 8, 9, 10};
    for (int i = 0; i < 6; ++i) {
        tt.src[i] = d_in[tin[i]];
        tt.dst[i] = (unsigned short*)(ws + off[tin[i] - 2]);
        tt.n[i] = in_sizes[tin[i]];
    }

    const long n8 = n_emb / 8;
    const int nEmb = (int)((n8 + 511) / 512);      // 2 chunks/thread
    const long gw8 = in_sizes[3] / 8;              // 4096 chunks
    const long w18 = in_sizes[6] / 8;              // 1024 chunks
    convert_all_kernel<<<85 + nEmb, 256, 0, stream>>>(
        d_in[2], emb_b, n8, nEmb,
        d_in[3], (unsigned short*)(ws + off[1]), gw8,
        d_in[6], (unsigned short*)(ws + off[4]), w18,
        d_in[4], d_in[7],                           // raw gwb, b1
        (unsigned short*)(ws + off_wg),
        (float*)(ws + off_bg),
        (int*)(ws + off_fl),
        tt);

    embed_matcher_fast<<<B, 256, 0, stream>>>(
        (const int*)d_in[0], (const int*)d_in[1],
        emb_b,
        (const unsigned short*)(ws + off[1]),   // gw
        (const unsigned short*)(ws + off_wg),   // Wg
        (const float*)(ws + off_bg),            // bg
        (const unsigned short*)(ws + off[2]),   // gwb
        (const unsigned short*)(ws + off[3]),   // gcnb
        (const unsigned short*)(ws + off[6]),   // w2
        (const unsigned short*)(ws + off[7]),   // b2
        (const unsigned short*)(ws + off[8]),   // temp
        (const int*)(ws + off_fl),              // precomputed dtype flag
        d_out);
}

// Round 4
// 220.367 us; speedup vs baseline: 1.2093x; 1.2093x over previous
//
#include <hip/hip_runtime.h>

#define EMBED_D 128
#define KNBR 50
#define STR 136       // X-tile row stride in u16 (128 + 8 pad)
#define NROWS 102     // 100 data rows (k*2+half) + 2 zero rows (100,101)
#define ZK 50         // sentinel k for tail lanes -> LDS rows 100/101
#define NTF 52        // Ns_T row stride in f32: [d][row], 52 rows (only 0..51 stored; 0..49 read)
#define XSTR 264      // (fallback only)
#define NSTR 136      // (fallback only)
#define MROWS 64

typedef __attribute__((ext_vector_type(8))) short short8;    // 8 bf16 (MFMA A/B frag)
typedef __attribute__((ext_vector_type(4))) float floatx4;   // MFMA C/D frag

__device__ __forceinline__ float b2f(unsigned short u) {
    union { unsigned int i; float f; } v;
    v.i = ((unsigned int)u) << 16;
    return v.f;
}
__device__ __forceinline__ unsigned short f2b(float f) {
    union { float f; unsigned int i; } v;
    v.f = f;
    return (unsigned short)((v.i + 0x7fffu + ((v.i >> 16) & 1u)) >> 16);  // RNE, finite-only
}

// 16-lane DPP all-reduce sum on the VALU pipe (not ds_swizzle/LDS).
__device__ __forceinline__ float dpp_row_sum16(float v) {
    int y;
    y = __builtin_amdgcn_update_dpp(0, __builtin_bit_cast(int, v), 0xB1, 0xF, 0xF, true);
    v += __builtin_bit_cast(float, y);
    y = __builtin_amdgcn_update_dpp(0, __builtin_bit_cast(int, v), 0x4E, 0xF, 0xF, true);
    v += __builtin_bit_cast(float, y);
    y = __builtin_amdgcn_update_dpp(0, __builtin_bit_cast(int, v), 0x124, 0xF, 0xF, true);
    v += __builtin_bit_cast(float, y);
    y = __builtin_amdgcn_update_dpp(0, __builtin_bit_cast(int, v), 0x128, 0xF, 0xF, true);
    v += __builtin_bit_cast(float, y);
    return v;
}

// bf16 emb data (N(0,0.02)) decodes to |v| < 0.15 everywhere; fp32 data has
// random low-mantissa words -> some finite |v| >= 1.0 with P ~ 1-2e-10.
__device__ __forceinline__ bool detect_bf16(const unsigned short* p) {
    float mx = 0.f;
#pragma unroll
    for (int i = 0; i < 64; ++i) {
        const float a = fabsf(b2f(p[i]));
        if (a < 3.0e38f && a > mx) mx = a;
    }
    return mx < 1.0f;
}

// ---------------- preprocessing (r12, proven: Wg/tiny/weights first, emb last) ----------------

struct TinyTensors {
    const void* src[6];
    unsigned short* dst[6];
    int n[6];
};

__device__ __forceinline__ void conv_chunk(const void* src, unsigned short* dst,
                                           long i, bool isbf) {
    if (isbf) {
        *(short8*)(dst + i * 8) = *(const short8*)((const unsigned short*)src + i * 8);
    } else {
        const float* p = (const float*)src + i * 8;
        const floatx4 a = *(const floatx4*)p;
        const floatx4 c = *(const floatx4*)(p + 4);
        short8 r;
        r[0] = (short)f2b(a[0]); r[1] = (short)f2b(a[1]);
        r[2] = (short)f2b(a[2]); r[3] = (short)f2b(a[3]);
        r[4] = (short)f2b(c[0]); r[5] = (short)f2b(c[1]);
        r[6] = (short)f2b(c[2]); r[7] = (short)f2b(c[3]);
        *(short8*)(dst + i * 8) = r;
    }
}

__global__ void convert_all_kernel(const void* __restrict__ emb_src, unsigned short* __restrict__ emb_dst,
                                   long n8, int nEmb,
                                   const void* __restrict__ gw_src, unsigned short* __restrict__ gw_dst,
                                   long gw8,
                                   const void* __restrict__ w1_src, unsigned short* __restrict__ w1_dst,
                                   long w18,
                                   const void* __restrict__ gwb_src, const void* __restrict__ b1_src,
                                   unsigned short* __restrict__ wg_dst,   // [64][256] bf16
                                   float* __restrict__ bg_dst,            // [64] f32
                                   int* __restrict__ flag_dst,            // [1] precomputed dtype flag
                                   TinyTensors tt) {
    __shared__ int isbfS;
    if (threadIdx.x == 0) isbfS = detect_bf16((const unsigned short*)emb_src) ? 1 : 0;
    __syncthreads();
    const bool isbf = (isbfS != 0);
    const int bid = blockIdx.x;

    if (bid < 64) {
        // Wg[j][f] = sum_d W1[j][d]*gw[d][f]; bg[j] = W1[j].gwb + b1[j].
        const int j = bid;
        const int f = threadIdx.x;
        float a = 0.f;
        if (isbf) {
            const unsigned short* w1u = (const unsigned short*)w1_src;
            const unsigned short* gwu = (const unsigned short*)gw_src;
            for (int d = 0; d < EMBED_D; ++d)
                a += b2f(w1u[j * EMBED_D + d]) * b2f(gwu[(long)d * 256 + f]);
        } else {
            const float* w1f = (const float*)w1_src;
            const float* gwf = (const float*)gw_src;
            for (int d = 0; d < EMBED_D; ++d)
                a += w1f[j * EMBED_D + d] * gwf[(long)d * 256 + f];
        }
        wg_dst[j * 256 + f] = f2b(a);
        if (f == 0) {
            float s = 0.f;
            if (isbf) {
                const unsigned short* w1u = (const unsigned short*)w1_src;
                const unsigned short* gu = (const unsigned short*)gwb_src;
                for (int d = 0; d < EMBED_D; ++d) s += b2f(w1u[j * EMBED_D + d]) * b2f(gu[d]);
                bg_dst[j] = s + b2f(((const unsigned short*)b1_src)[j]);
            } else {
                const float* w1f = (const float*)w1_src;
                const float* gf = (const float*)gwb_src;
                for (int d = 0; d < EMBED_D; ++d) s += w1f[j * EMBED_D + d] * gf[d];
                bg_dst[j] = s + ((const float*)b1_src)[j];
            }
        }
    } else if (bid == 64) {
        if (threadIdx.x == 0) *flag_dst = isbf ? 1 : 0;
#pragma unroll
        for (int ti = 0; ti < 6; ++ti) {
            const int n = tt.n[ti];
            for (int i = threadIdx.x; i < n; i += 256) {
                const float v = isbf ? b2f(((const unsigned short*)tt.src[ti])[i])
                                     : ((const float*)tt.src[ti])[i];
                tt.dst[ti][i] = f2b(v);
            }
        }
    } else if (bid < 85) {
        const long q = (long)(bid - 65) * 256 + threadIdx.x;   // gw8+w18 = 5120 chunks
        if (q < gw8) conv_chunk(gw_src, gw_dst, q, isbf);
        else if (q < gw8 + w18) conv_chunk(w1_src, w1_dst, q - gw8, isbf);
    } else {
        const long i0 = (long)(bid - 85) * 512 + threadIdx.x;  // 2 chunks/thread
        if (i0 < n8) conv_chunk(emb_src, emb_dst, i0, isbf);
        const long i1 = i0 + 256;
        if (i1 < n8) conv_chunk(emb_src, emb_dst, i1, isbf);
    }
}

// ---------------- main kernel ----------------
// r15 post-mortem: WRITE_SIZE is the spill telltale. r14 (launch_bounds(256,5))
// already spilled ~20 B/thread (WRITE 4->44 MB) but won on occupancy; r15's
// global_load_lds gather ADDED pressure (syms + swizzle addr math) -> spills
// doubled (WRITE 95 MB, +57 us of scratch traffic). Reverted to the r14
// structure. r16 keeps the 48-VGPR/5-wave bucket and removes the spill source:
//  - P0 gather split into 4+3 batches: in-flight data capped at 16 VGPRs
//    (4-deep x 20 waves/CU = 80 KB in flight, still covers ~900cy HBM latency)
//  - P1 A-frags scoped per-m (compiler keeps a 1-2 deep rotation, ~8 VGPRs,
//    instead of a materialized A[4] = 16)
// Success signal: WRITE_SIZE back to ~4 MB.

__global__ __launch_bounds__(256, 5)
void embed_matcher_fast(const int* __restrict__ entity, const int* __restrict__ conn,
                        const unsigned short* __restrict__ emb,   // bf16 staged
                        const unsigned short* __restrict__ gw,    // [128][256] bf16
                        const unsigned short* __restrict__ wg,    // [64][256] bf16 (W1.gw)
                        const float* __restrict__ bgp,            // [64] f32 (W1.gwb + b1)
                        const unsigned short* __restrict__ gwb,
                        const unsigned short* __restrict__ gcnb,
                        const unsigned short* __restrict__ w2,
                        const unsigned short* __restrict__ b2v,
                        const unsigned short* __restrict__ temp,
                        const int* __restrict__ flagp,            // precomputed output-dtype flag
                        void* __restrict__ out)
{
    // Phase 1: X tile 102 x 136 u16 = 27744 B.
    // Phase 2: Ns_T 128 x 52 f32 = 26624 B (aliased; X size dominates the union).
    __shared__ __align__(16) unsigned short Xs[NROWS * STR];   // 27744 B union buffer
    __shared__ __align__(16) float selfE[EMBED_D];
    __shared__ float scoresP[4 * MROWS];   // per-wave partials (no LDS atomics)
    __shared__ float glP[4 * MROWS];
    __shared__ __align__(16) float attnS[MROWS];
    __shared__ int flagS;

    float* NsF = (float*)Xs;               // phase-2 alias (26624 <= 27744 B)

    const int t = threadIdx.x;
    const int b = blockIdx.x;
    const int lane = t & 63;
    const int wave = t >> 6;
    const int l15 = lane & 15;
    const int quad = lane >> 4;
    const int cbase = b * (KNBR * 2);

    const int k3 = 48 + l15;
    const int rowk3 = (k3 < KNBR) ? k3 : ZK;             // m=3 tail -> zero rows

    floatx4 acc[4][3];                                   // [m][T]: T=0,1 gw-slices, T=2 wg
    const floatx4 fzero = {0.f, 0.f, 0.f, 0.f};
#pragma unroll
    for (int m = 0; m < 4; ++m)
#pragma unroll
        for (int T = 0; T < 3; ++T) acc[m][T] = fzero;

    // ---- P0: gather in two batches (peak pressure: 4 syms + 4 short8 in flight) ----
    {
        // batch 0: chunks 0..3 (c = t + 256*i < 1024, always valid)
        int syms0[4];
#pragma unroll
        for (int i = 0; i < 4; ++i) {
            const int c = t + 256 * i;                   // c = r*16 + j, r = k*2+half
            syms0[i] = conn[cbase + (c >> 4)];
        }
#pragma unroll
        for (int i = 0; i < 4; ++i) {
            const int c = t + 256 * i;
            const short8 v = *(const short8*)(emb + (long)syms0[i] * EMBED_D + (c & 15) * 8);
            *(short8*)(Xs + (c >> 4) * STR + (c & 15) * 8) = v;
        }
        // batch 1: chunks 4..6 (tail-guarded)
        int syms1[3];
#pragma unroll
        for (int i = 0; i < 3; ++i) {
            const int c = t + 256 * (i + 4);
            syms1[i] = (c < KNBR * 2 * 16) ? conn[cbase + (c >> 4)] : 0;
        }
#pragma unroll
        for (int i = 0; i < 3; ++i) {
            const int c = t + 256 * (i + 4);
            if (c < KNBR * 2 * 16) {
                const short8 v = *(const short8*)(emb + (long)syms1[i] * EMBED_D + (c & 15) * 8);
                *(short8*)(Xs + (c >> 4) * STR + (c & 15) * 8) = v;
            }
        }
        const short8 z8 = {0, 0, 0, 0, 0, 0, 0, 0};
        if (t < 34)                                      // zero rows 100,101: 272 elems
            *(short8*)(Xs + ZK * 2 * STR + t * 8) = z8;
        if (t < EMBED_D) selfE[t] = b2f(emb[(long)entity[b] * EMBED_D + t]);
        if (t == 0) flagS = *flagp;
    }
    __syncthreads();

    const unsigned short* gB0 = gw + (wave * 32 + l15) * 256;       // B row, n-tile 0
    const unsigned short* gB1 = gB0 + 16 * 256;                     // n-tile 1
    const unsigned short* gWg = wg + (wave * 16 + l15) * 256;       // wg n-tile

    // ---- P1: C[64 x 160] = X(64x256) . [gw | Wg]^T ----
    // B0/B1 pipelined 1 deep; Bg loaded in-loop (L1/L2-hot 32KB table).
    // A-frags scoped per-m: compiler keeps a short rotation instead of A[4].
    short8 B0c = *(const short8*)(gB0 + quad * 8);
    short8 B1c = *(const short8*)(gB1 + quad * 8);
#pragma unroll
    for (int ft = 0; ft < 8; ++ft) {
        const short8 Bgc = *(const short8*)(gWg + ft * 32 + quad * 8);
        short8 B0n, B1n;
        if (ft < 7) {                                    // prefetch next B frags
            const int kn = (ft + 1) * 32 + quad * 8;
            B0n = *(const short8*)(gB0 + kn);
            B1n = *(const short8*)(gB1 + kn);
        }
        const int half = ft >> 2;
        const int cofs = (ft & 3) * 32 + quad * 8;       // col within the 128-wide half
#pragma unroll
        for (int m = 0; m < 4; ++m) {
            const int rr = (m < 3) ? (m * 16 + l15) : rowk3;
            const short8 Am = *(const short8*)(Xs + (rr * 2 + half) * STR + cofs);
            acc[m][0] = __builtin_amdgcn_mfma_f32_16x16x32_bf16(Am, B0c, acc[m][0], 0, 0, 0);
            acc[m][1] = __builtin_amdgcn_mfma_f32_16x16x32_bf16(Am, B1c, acc[m][1], 0, 0, 0);
            acc[m][2] = __builtin_amdgcn_mfma_f32_16x16x32_bf16(Am, Bgc, acc[m][2], 0, 0, 0);
        }
        if (ft < 7) { B0c = B0n; B1c = B1n; }
    }
    __syncthreads();   // X dead; buffer becomes Ns_T (f32)

    // ---- Epilogue: bias + fp32 Ns_T b128 stores + score & gate partials via DPP ----
    // C/D layout: lane (l15,quad) holds rows m*16+quad*4+r, cols wave*32+T*16+l15
    // (T=2 -> wg col wave*16+l15).
    // Rows >= 52 are never read (softmax masks k >= 50), so m==3 stores only
    // quad==0 (rows 48..51) to stay inside the NTF=52 stride.
    {
        const int dcol0 = wave * 32 + l15;
        const int dcol1 = dcol0 + 16;
        const float bias0 = b2f(gwb[dcol0]);
        const float bias1 = b2f(gwb[dcol1]);
        const float se0 = selfE[dcol0];
        const float se1 = selfE[dcol1];
        const float bgj = bgp[wave * 16 + l15];
        const float w2j = b2f(w2[wave * 16 + l15]);
#pragma unroll
        for (int m = 0; m < 4; ++m) {
            const int rbase = m * 16 + quad * 4;
            floatx4 v0, v1;
            float sc[4], gl[4];
#pragma unroll
            for (int r = 0; r < 4; ++r) {
                v0[r] = acc[m][0][r] + bias0;
                v1[r] = acc[m][1][r] + bias1;
                sc[r] = se0 * v0[r] + se1 * v1[r];
                gl[r] = fmaxf(acc[m][2][r] + bgj, 0.f) * w2j;
            }
            if (m < 3 || quad == 0) {
                *(floatx4*)(NsF + dcol0 * NTF + rbase) = v0;
                *(floatx4*)(NsF + dcol1 * NTF + rbase) = v1;
            }
#pragma unroll
            for (int r = 0; r < 4; ++r) {
                sc[r] = dpp_row_sum16(sc[r]);   // VALU-pipe 16-lane reduce
                gl[r] = dpp_row_sum16(gl[r]);
            }
            const float sv = (l15 == 0) ? sc[0] : ((l15 == 1) ? sc[1] : ((l15 == 2) ? sc[2] : sc[3]));
            const float gv = (l15 == 0) ? gl[0] : ((l15 == 1) ? gl[1] : ((l15 == 2) ? gl[2] : gl[3]));
            if (l15 < 4) {
                scoresP[wave * MROWS + rbase + l15] = sv;
                glP[wave * MROWS + rbase + l15] = gv;
            }
        }
    }
    __syncthreads();

    // ---- softmax + gate fold (wave 0) ----
    if (t < 64) {
        const float ssum = scoresP[t] + scoresP[64 + t] + scoresP[128 + t] + scoresP[192 + t];
        const float s = (t < KNBR) ? ssum * 0.088388347648318447f : -INFINITY;  // /sqrt(128)
        float mx = s;
#pragma unroll
        for (int o = 32; o > 0; o >>= 1) mx = fmaxf(mx, __shfl_xor(mx, o));
        const float e = (t < KNBR) ? expf(s - mx) : 0.f;
        float sum = e;
#pragma unroll
        for (int o = 32; o > 0; o >>= 1) sum += __shfl_xor(sum, o);
        float a = e / sum;
        if (t < KNBR) {
            const float invT = 1.0f / b2f(temp[0]);
            const float logit = glP[t] + glP[64 + t] + glP[128 + t] + glP[192 + t] + b2f(b2v[0]);
            a *= 1.0f / (1.0f + expf(-logit * invT));
        }
        attnS[t] = a;   // 0 for t >= KNBR
    }
    __syncthreads();

    // ---- P4b: out[d] = tanh(max_k(attn*nbr) + gcn_b), b128 fp32 reads ----
    if (t < EMBED_D) {
        const float* nr = NsF + t * NTF;
        float mx = -INFINITY;
#pragma unroll
        for (int c = 0; c < 12; ++c) {                   // rows 0..47
            const floatx4 nv = *(const floatx4*)(nr + c * 4);
            const floatx4 av = *(const floatx4*)(attnS + c * 4);
#pragma unroll
            for (int j = 0; j < 4; ++j)
                mx = fmaxf(mx, av[j] * nv[j]);
        }
        mx = fmaxf(mx, attnS[48] * nr[48]);
        mx = fmaxf(mx, attnS[49] * nr[49]);
        const float o = tanhf(mx + b2f(gcnb[t]));
        if (flagS)
            ((unsigned short*)out)[(long)b * EMBED_D + t] = f2b(o);
        else
            ((float*)out)[(long)b * EMBED_D + t] = o;
    }
}

// ---------------- fallback (round-2 proven kernel, used only if ws too small) ----------------

template <bool BF16IN>
__device__ __forceinline__ short8 load8g(const void* base, long off) {
    if constexpr (BF16IN) {
        return *(const short8*)((const unsigned short*)base + off);
    } else {
        const float* p = (const float*)base + off;
        const floatx4 a = *(const floatx4*)p;
        const floatx4 c = *(const floatx4*)(p + 4);
        short8 r;
        r[0] = (short)f2b(a[0]); r[1] = (short)f2b(a[1]);
        r[2] = (short)f2b(a[2]); r[3] = (short)f2b(a[3]);
        r[4] = (short)f2b(c[0]); r[5] = (short)f2b(c[1]);
        r[6] = (short)f2b(c[2]); r[7] = (short)f2b(c[3]);
        return r;
    }
}
template <bool BF16IN>
__device__ __forceinline__ float loadSg(const void* base, long off) {
    if constexpr (BF16IN) return b2f(((const unsigned short*)base)[off]);
    else return ((const float*)base)[off];
}

template <bool BF16IN>
__device__ __forceinline__ void body_fb(
    const int* entity, const int* conn, const void* emb, const void* gw,
    const void* gwb, const void* gcnb, const void* w1, const void* b1,
    const void* w2, const void* b2, const void* temp, void* out,
    unsigned short* Xs, unsigned short* Ns,
    float* selfE, float* scoresS, float* attnS, float* gsumS)
{
    const int t = threadIdx.x, b = blockIdx.x;
    const int lane = t & 63, wave = t >> 6, l15 = lane & 15, quad = lane >> 4;
    short8 Bfrag[8][2];
#pragma unroll
    for (int ft = 0; ft < 8; ++ft)
#pragma unroll
        for (int nn = 0; nn < 2; ++nn)
            Bfrag[ft][nn] = load8g<BF16IN>(gw, (wave * 32 + nn * 16 + l15) * 256 + ft * 32 + quad * 8);
    short8 W1frag[4];
#pragma unroll
    for (int ft = 0; ft < 4; ++ft)
        W1frag[ft] = load8g<BF16IN>(w1, (wave * 16 + l15) * 128 + ft * 32 + quad * 8);
    const float b1j = loadSg<BF16IN>(b1, wave * 16 + l15);
    const float w2j = loadSg<BF16IN>(w2, wave * 16 + l15);
    {
        const int cbase = b * (KNBR * 2);
        for (int c = t; c < KNBR * 2 * 16; c += 256) {
            const int r = c >> 4, j = c & 15;
            const int sym = conn[cbase + r];
            *(short8*)(Xs + (r >> 1) * XSTR + (r & 1) * 128 + j * 8) =
                load8g<BF16IN>(emb, (long)sym * EMBED_D + j * 8);
        }
        for (int i = t; i < (MROWS - KNBR) * 256; i += 256)
            Xs[(KNBR + (i >> 8)) * XSTR + (i & 255)] = 0;
        if (t < EMBED_D) selfE[t] = loadSg<BF16IN>(emb, (long)entity[b] * EMBED_D + t);
        if (t < MROWS) gsumS[t] = loadSg<BF16IN>(b2, 0);
    }
    __syncthreads();
    floatx4 acc[4][2];
    const floatx4 fzero = {0.f, 0.f, 0.f, 0.f};
#pragma unroll
    for (int m = 0; m < 4; ++m)
#pragma unroll
        for (int nn = 0; nn < 2; ++nn) acc[m][nn] = fzero;
#pragma unroll
    for (int ft = 0; ft < 8; ++ft) {
        short8 A[4];
#pragma unroll
        for (int m = 0; m < 4; ++m)
            A[m] = *(const short8*)(Xs + (m * 16 + l15) * XSTR + ft * 32 + quad * 8);
#pragma unroll
        for (int m = 0; m < 4; ++m)
#pragma unroll
            for (int nn = 0; nn < 2; ++nn)
                acc[m][nn] = __builtin_amdgcn_mfma_f32_16x16x32_bf16(A[m], Bfrag[ft][nn], acc[m][nn], 0, 0, 0);
    }
#pragma unroll
    for (int nn = 0; nn < 2; ++nn) {
        const int dcol = wave * 32 + nn * 16 + l15;
        const float bias = loadSg<BF16IN>(gwb, dcol);
#pragma unroll
        for (int m = 0; m < 4; ++m)
#pragma unroll
            for (int r = 0; r < 4; ++r)
                Ns[(m * 16 + quad * 4 + r) * NSTR + dcol] = f2b(acc[m][nn][r] + bias);
    }
    __syncthreads();
    {
        const int k = t >> 2, q = t & 3;
        float p = 0.f;
        if (k < KNBR) {
            const unsigned short* nr = Ns + k * NSTR + q * 32;
            const float* se = selfE + q * 32;
#pragma unroll
            for (int i = 0; i < 32; ++i) p += se[i] * b2f(nr[i]);
        }
        p += __shfl_xor(p, 1);
        p += __shfl_xor(p, 2);
        if (k < KNBR && q == 0) scoresS[k] = p * 0.088388347648318447f;
    }
    __syncthreads();
    if (t < 64) {
        const float s = (t < KNBR) ? scoresS[t] : -INFINITY;
        float mx = s;
#pragma unroll
        for (int o = 32; o > 0; o >>= 1) mx = fmaxf(mx, __shfl_xor(mx, o));
        const float e = (t < KNBR) ? expf(s - mx) : 0.f;
        float sum = e;
#pragma unroll
        for (int o = 32; o > 0; o >>= 1) sum += __shfl_xor(sum, o);
        attnS[t] = e / sum;
    }
    floatx4 acc2[4];
#pragma unroll
    for (int m = 0; m < 4; ++m) acc2[m] = fzero;
#pragma unroll
    for (int ft = 0; ft < 4; ++ft) {
        short8 A2[4];
#pragma unroll
        for (int m = 0; m < 4; ++m)
            A2[m] = *(const short8*)(Ns + (m * 16 + l15) * NSTR + ft * 32 + quad * 8);
#pragma unroll
        for (int m = 0; m < 4; ++m)
            acc2[m] = __builtin_amdgcn_mfma_f32_16x16x32_bf16(A2[m], W1frag[ft], acc2[m], 0, 0, 0);
    }
#pragma unroll
    for (int m = 0; m < 4; ++m)
#pragma unroll
        for (int r = 0; r < 4; ++r) {
            float c = fmaxf(acc2[m][r] + b1j, 0.f) * w2j;
            c += __shfl_xor(c, 1); c += __shfl_xor(c, 2);
            c += __shfl_xor(c, 4); c += __shfl_xor(c, 8);
            if (l15 == 0) atomicAdd(&gsumS[m * 16 + quad * 4 + r], c);
        }
    __syncthreads();
    if (t < KNBR) {
        const float invT = 1.0f / loadSg<BF16IN>(temp, 0);
        attnS[t] *= 1.0f / (1.0f + expf(-gsumS[t] * invT));
    }
    __syncthreads();
    if (t < EMBED_D) {
        float mx = -INFINITY;
        for (int k = 0; k < KNBR; ++k)
            mx = fmaxf(mx, attnS[k] * b2f(Ns[k * NSTR + t]));
        const float o = tanhf(mx + loadSg<BF16IN>(gcnb, t));
        if constexpr (BF16IN)
            ((unsigned short*)out)[(long)b * EMBED_D + t] = f2b(o);
        else
            ((float*)out)[(long)b * EMBED_D + t] = o;
    }
}

__global__ __launch_bounds__(256, 2)
void embed_matcher_fallback(const int* entity, const int* conn, const void* emb,
                            const void* gw, const void* gwb, const void* gcnb,
                            const void* w1, const void* b1, const void* w2,
                            const void* b2, const void* temp, void* out)
{
    __shared__ __align__(16) unsigned short Xs[MROWS * XSTR];
    __shared__ __align__(16) unsigned short Ns[MROWS * NSTR];
    __shared__ float selfE[EMBED_D];
    __shared__ float scoresS[MROWS];
    __shared__ float attnS[MROWS];
    __shared__ float gsumS[MROWS];
    if (detect_bf16((const unsigned short*)emb))
        body_fb<true>(entity, conn, emb, gw, gwb, gcnb, w1, b1, w2, b2, temp, out,
                      Xs, Ns, selfE, scoresS, attnS, gsumS);
    else
        body_fb<false>(entity, conn, emb, gw, gwb, gcnb, w1, b1, w2, b2, temp, out,
                       Xs, Ns, selfE, scoresS, attnS, gsumS);
}

// ---------------- launcher ----------------

static inline size_t align256(size_t x) { return (x + 255) & ~(size_t)255; }

extern "C" void kernel_launch(void* const* d_in, const int* in_sizes, int n_in,
                              void* d_out, int out_size, void* d_ws, size_t ws_size,
                              hipStream_t stream) {
    (void)n_in; (void)out_size;
    const int B = in_sizes[0];  // 8192

    // ws layout: bf16 copies of all float tensors + Wg (bf16) + bg (f32) + flag
    const long n_emb = in_sizes[2];
    size_t off[9], cur = 0;
    const int ns[8] = {in_sizes[3], in_sizes[4], in_sizes[5], in_sizes[6],
                       in_sizes[7], in_sizes[8], in_sizes[9], in_sizes[10]};
    off[0] = 0; cur = align256((size_t)n_emb * 2);                      // emb
    for (int i = 0; i < 8; ++i) { off[i + 1] = cur; cur = align256(cur + (size_t)ns[i] * 2); }
    const size_t off_wg = cur; cur = align256(cur + 64 * 256 * 2);      // Wg bf16
    const size_t off_bg = cur; cur = align256(cur + 64 * 4);            // bg f32
    const size_t off_fl = cur; cur = align256(cur + 4);                 // dtype flag

    if (ws_size < cur) {
        embed_matcher_fallback<<<B, 256, 0, stream>>>(
            (const int*)d_in[0], (const int*)d_in[1],
            d_in[2], d_in[3], d_in[4], d_in[5],
            d_in[6], d_in[7], d_in[8], d_in[9], d_in[10], d_out);
        return;
    }

    char* ws = (char*)d_ws;
    unsigned short* emb_b = (unsigned short*)(ws + off[0]);

    // tiny tensors: gwb, gcnb, b1, w2, b2, temp  (input idx 4,5,7,8,9,10)
    TinyTensors tt;
    const int tin[6] = {4, 5, 7, 8, 9, 10};
    for (int i = 0; i < 6; ++i) {
        tt.src[i] = d_in[tin[i]];
        tt.dst[i] = (unsigned short*)(ws + off[tin[i] - 2]);
        tt.n[i] = in_sizes[tin[i]];
    }

    const long n8 = n_emb / 8;
    const int nEmb = (int)((n8 + 511) / 512);      // 2 chunks/thread
    const long gw8 = in_sizes[3] / 8;              // 4096 chunks
    const long w18 = in_sizes[6] / 8;              // 1024 chunks
    convert_all_kernel<<<85 + nEmb, 256, 0, stream>>>(
        d_in[2], emb_b, n8, nEmb,
        d_in[3], (unsigned short*)(ws + off[1]), gw8,
        d_in[6], (unsigned short*)(ws + off[4]), w18,
        d_in[4], d_in[7],                           // raw gwb, b1
        (unsigned short*)(ws + off_wg),
        (float*)(ws + off_bg),
        (int*)(ws + off_fl),
        tt);

    embed_matcher_fast<<<B, 256, 0, stream>>>(
        (const int*)d_in[0], (const int*)d_in[1],
        emb_b,
        (const unsigned short*)(ws + off[1]),   // gw
        (const unsigned short*)(ws + off_wg),   // Wg
        (const float*)(ws + off_bg),            // bg
        (const unsigned short*)(ws + off[2]),   // gwb
        (const unsigned short*)(ws + off[3]),   // gcnb
        (const unsigned short*)(ws + off[6]),   // w2
        (const unsigned short*)(ws + off[7]),   // b2
        (const unsigned short*)(ws + off[8]),   // temp
        (const int*)(ws + off_fl),              // precomputed dtype flag
        d_out);
}